// Round 7
// baseline (573.314 us; speedup 1.0000x reference)
//
#include <hip/hip_runtime.h>
#include <math.h>

#define CC   128
#define HH   16
#define WW   16
#define BB   32
#define VV   8192
#define NELEM (BB*CC*HH*WW)   // 1,048,576

typedef short short8 __attribute__((ext_vector_type(8)));
typedef float floatx4 __attribute__((ext_vector_type(4)));

#define CSTR 136   // conv LDS row stride in bf16 elems (128 + 8 pad)

// ---------------- hi/lo bf16 split pack (RNE both) ----------------
__device__ __forceinline__ uint32_t pack_hilo(float x) {
    uint32_t u = __float_as_uint(x);
    uint32_t hb = (u + 0x7fffu + ((u >> 16) & 1u)) & 0xffff0000u;
    float hf = __uint_as_float(hb);
    float lo = x - hf;
    uint32_t ul = __float_as_uint(lo);
    uint32_t lb = ((ul + 0x7fffu + ((ul >> 16) & 1u)) >> 16) & 0xffffu;
    return hb | lb;
}

// ---------------- e_sq + codebook hi/lo plane split + lacc zero ----------------
__global__ void esq_pack(const float* __restrict__ emb, float* __restrict__ esq,
                         short* __restrict__ ephi, short* __restrict__ eplo,
                         float* __restrict__ lacc) {
    int t = blockIdx.x * 256 + threadIdx.x;
    int v = t >> 4, g = t & 15;
    const float* row = emb + (size_t)v * CC + g * 8;
    float4 a = *(const float4*)row;
    float4 b = *(const float4*)(row + 4);
    float s = a.x*a.x + a.y*a.y + a.z*a.z + a.w*a.w
            + b.x*b.x + b.y*b.y + b.z*b.z + b.w*b.w;
    s += __shfl_xor(s, 1, 64);
    s += __shfl_xor(s, 2, 64);
    s += __shfl_xor(s, 4, 64);
    s += __shfl_xor(s, 8, 64);
    if (g == 0) esq[v] = s;
    float vals[8] = {a.x, a.y, a.z, a.w, b.x, b.y, b.z, b.w};
    short hs[8], ls[8];
#pragma unroll
    for (int j = 0; j < 8; j++) {
        uint32_t u = pack_hilo(vals[j]);
        hs[j] = (short)(u >> 16);
        ls[j] = (short)(u & 0xffffu);
    }
    *(short8*)(ephi + (size_t)v * CC + g * 8) = *(short8*)hs;
    *(short8*)(eplo + (size_t)v * CC + g * 8) = *(short8*)ls;
    if (t == 0) lacc[0] = 0.f;
}

// ---------------- pre-transpose + split conv weights: Wt[kphi][kk][cout][cin] ----------------
__global__ void prepack_w(const float* __restrict__ pw, short* __restrict__ Whi,
                          short* __restrict__ Wlo) {
    int id = blockIdx.x * 256 + threadIdx.x;      // 65536 = 4*128*128
    int ci = id & 127, cout = (id >> 7) & 127, kp = id >> 14;
    const float* src = pw + ((size_t)(kp * CC + cout) * CC + ci) * 9;
#pragma unroll
    for (int kk = 0; kk < 9; kk++) {
        uint32_t u = pack_hilo(src[kk]);
        size_t o = ((size_t)(kp * 9 + kk) * CC + cout) * CC + ci;
        Whi[o] = (short)(u >> 16);
        Wlo[o] = (short)(u & 0xffffu);
    }
}

// ---------------- pooled residual (f - f_hat) -> hi/lo planes ----------------
template <bool FIRSTP>
__global__ void pool_pack(const float* __restrict__ f, const float* __restrict__ fh,
                          short* __restrict__ rh, short* __restrict__ rl, int pn) {
    int id = blockIdx.x * 256 + threadIdx.x;
    int c = id % CC;
    int n = id / CC;
    int px = n % pn;
    int py = (n / pn) % pn;
    int b  = n / (pn * pn);
    int s  = HH / pn;
    size_t o = (((size_t)b * CC + c) * HH + py * s) * WW + px * s;
    float acc = 0.f;
    for (int dy = 0; dy < s; dy++)
        for (int dx = 0; dx < s; dx++)
            acc += FIRSTP ? f[o + dy * WW + dx] : (f[o + dy * WW + dx] - fh[o + dy * WW + dx]);
    uint32_t u = pack_hilo(acc * (1.f / (float)(s * s)));
    rh[id] = (short)(u >> 16);
    rl[id] = (short)(u & 0xffffu);
}

// ---------------- MFMA distance v4: no spills (per-kc A loads), 3 products ----------------
// grid (qb, vslices); block 256 = 4 waves: qh=w&1, vh=w>>1. Wave: 64 q x 64 v quadrant.
__global__ __launch_bounds__(256, 2)
void dist_mfma(const short* __restrict__ rphi, const short* __restrict__ rplo,
               const short* __restrict__ ephi, const short* __restrict__ eplo,
               const float* __restrict__ esq,
               float* __restrict__ pbD, int* __restrict__ pbI,
               int N, int vtPB) {
    const int tid  = threadIdx.x;
    const int wave = tid >> 6, lane = tid & 63;
    const int quad = lane >> 4, l15 = lane & 15;
    const int qh = wave & 1, vh = wave >> 1;
    const int qb0 = blockIdx.x * 128;
    const int vslices = gridDim.y;
    const int vbase = blockIdx.y * vtPB * 128;

    size_t arow[4];
#pragma unroll
    for (int ti = 0; ti < 4; ti++)
        arow[ti] = (size_t)(qb0 + qh * 64 + ti * 16 + l15) * CC + quad * 8;

    float bD[4][4];
    int   bI[4][4];
#pragma unroll
    for (int ti = 0; ti < 4; ti++)
#pragma unroll
        for (int r = 0; r < 4; r++) { bD[ti][r] = INFINITY; bI[ti][r] = 0; }

    for (int vt = 0; vt < vtPB; vt++) {
        const int v0 = vbase + vt * 128;
        floatx4 acc[4][4];
        floatx4 z = {0.f, 0.f, 0.f, 0.f};
#pragma unroll
        for (int ti = 0; ti < 4; ti++)
#pragma unroll
            for (int tj = 0; tj < 4; tj++) acc[ti][tj] = z;

        size_t brow[4];
#pragma unroll
        for (int tj = 0; tj < 4; tj++)
            brow[tj] = (size_t)(v0 + vh * 64 + tj * 16 + l15) * CC + quad * 8;

#pragma unroll 1
        for (int kc = 0; kc < 4; kc++) {
            const int ko = kc * 32;
            short8 av[4], aw[4], bh[4], bl[4];
#pragma unroll
            for (int ti = 0; ti < 4; ti++) {
                av[ti] = *(const short8*)(rphi + arow[ti] + ko);
                aw[ti] = *(const short8*)(rplo + arow[ti] + ko);
            }
#pragma unroll
            for (int tj = 0; tj < 4; tj++) {
                bh[tj] = *(const short8*)(ephi + brow[tj] + ko);
                bl[tj] = *(const short8*)(eplo + brow[tj] + ko);
            }
#pragma unroll
            for (int ti = 0; ti < 4; ti++)
#pragma unroll
                for (int tj = 0; tj < 4; tj++) {
                    acc[ti][tj] = __builtin_amdgcn_mfma_f32_16x16x32_bf16(av[ti], bh[tj], acc[ti][tj], 0, 0, 0);
                    acc[ti][tj] = __builtin_amdgcn_mfma_f32_16x16x32_bf16(aw[ti], bh[tj], acc[ti][tj], 0, 0, 0);
                    acc[ti][tj] = __builtin_amdgcn_mfma_f32_16x16x32_bf16(av[ti], bl[tj], acc[ti][tj], 0, 0, 0);
                }
        }

        // dist = esq - 2*dot; v ascending per lane -> strict < keeps first min
#pragma unroll
        for (int tj = 0; tj < 4; tj++) {
            int vg = v0 + vh * 64 + tj * 16 + l15;
            float ev = esq[vg];
#pragma unroll
            for (int ti = 0; ti < 4; ti++)
#pragma unroll
                for (int r = 0; r < 4; r++) {
                    float d = fmaf(-2.f, acc[ti][tj][r], ev);
                    if (d < bD[ti][r]) { bD[ti][r] = d; bI[ti][r] = vg; }
                }
        }
    }

    // cross-lane reduce within 16-lane groups (same q, different v), tie -> lower v
#pragma unroll
    for (int ti = 0; ti < 4; ti++)
#pragma unroll
        for (int r = 0; r < 4; r++) {
            float d = bD[ti][r];
            int   v = bI[ti][r];
#pragma unroll
            for (int m = 1; m <= 8; m <<= 1) {
                float od = __shfl_xor(d, m, 64);
                int   ov = __shfl_xor(v, m, 64);
                if (od < d || (od == d && ov < v)) { d = od; v = ov; }
            }
            if (l15 == 0) {
                int q = qb0 + qh * 64 + ti * 16 + quad * 4 + r;
                if (q < N) {
                    size_t o = (size_t)q * (vslices * 2) + blockIdx.y * 2 + vh;
                    pbD[o] = d;
                    pbI[o] = v;
                }
            }
        }
}

// ---------------- Keys cubic a=-0.5 (matches jax) ----------------
__device__ __forceinline__ float cubic_k(float x) {
    if (x <= 1.f) return (1.5f * x - 2.5f) * x * x + 1.f;
    if (x < 2.f)  return ((-0.5f * x + 2.5f) * x - 4.f) * x + 2.f;
    return 0.f;
}

// ---------------- fused argmin + upsample -> h planes ----------------
template <int PN>
__global__ __launch_bounds__(256)
void upsample_pack(const float* __restrict__ emb,
                   const float* __restrict__ pbD, const int* __restrict__ pbI, int vsplit,
                   short* __restrict__ hhi, short* __restrict__ hlo,
                   float* __restrict__ hfp) {
    const int t = threadIdx.x;
    const int x = t & 15, y = t >> 4;
    const int b = blockIdx.x >> 4;
    const int c0 = (blockIdx.x & 15) * 8;

    float val[8];

    if (PN == 16) {
        int q = b * 256 + t;
        float bd = pbD[(size_t)q * vsplit];
        int   bi = pbI[(size_t)q * vsplit];
        for (int j = 1; j < vsplit; j++) {
            float d  = pbD[(size_t)q * vsplit + j];
            int   i2 = pbI[(size_t)q * vsplit + j];
            if (d < bd || (d == bd && i2 < bi)) { bd = d; bi = i2; }
        }
        float4 v0 = *(const float4*)(emb + (size_t)bi * CC + c0);
        float4 v1 = *(const float4*)(emb + (size_t)bi * CC + c0 + 4);
        val[0]=v0.x; val[1]=v0.y; val[2]=v0.z; val[3]=v0.w;
        val[4]=v1.x; val[5]=v1.y; val[6]=v1.z; val[7]=v1.w;
    } else {
        __shared__ int idxL[PN * PN];
        __shared__ float S[PN * PN][8];
        if (t < PN * PN) {
            int q = b * PN * PN + t;
            float bd = pbD[(size_t)q * vsplit];
            int   bi = pbI[(size_t)q * vsplit];
            for (int j = 1; j < vsplit; j++) {
                float d  = pbD[(size_t)q * vsplit + j];
                int   i2 = pbI[(size_t)q * vsplit + j];
                if (d < bd || (d == bd && i2 < bi)) { bd = d; bi = i2; }
            }
            idxL[t] = bi;
        }
        __syncthreads();
        if (t < PN * PN) {
            float4 v0 = *(const float4*)(emb + (size_t)idxL[t] * CC + c0);
            float4 v1 = *(const float4*)(emb + (size_t)idxL[t] * CC + c0 + 4);
            S[t][0]=v0.x; S[t][1]=v0.y; S[t][2]=v0.z; S[t][3]=v0.w;
            S[t][4]=v1.x; S[t][5]=v1.y; S[t][6]=v1.z; S[t][7]=v1.w;
        }
        __syncthreads();

        const float sc = (float)PN / 16.f;
        float sy = (y + 0.5f) * sc - 0.5f;
        float sx = (x + 0.5f) * sc - 0.5f;
        int iy0 = (int)floorf(sy) - 1;
        int ix0 = (int)floorf(sx) - 1;
        float wy[4], wx[4];
        float ssy = 0.f, ssx = 0.f;
#pragma unroll
        for (int k = 0; k < 4; k++) {
            int iy = iy0 + k, ix = ix0 + k;
            float a = (iy >= 0 && iy < PN) ? cubic_k(fabsf(sy - (float)iy)) : 0.f;
            float bb = (ix >= 0 && ix < PN) ? cubic_k(fabsf(sx - (float)ix)) : 0.f;
            wy[k] = a; ssy += a;
            wx[k] = bb; ssx += bb;
        }
        float ry = 1.f / ssy, rx = 1.f / ssx;
#pragma unroll
        for (int k = 0; k < 4; k++) { wy[k] *= ry; wx[k] *= rx; }

#pragma unroll
        for (int j = 0; j < 8; j++) val[j] = 0.f;
#pragma unroll
        for (int k4 = 0; k4 < 4; k4++) {
            int iy = iy0 + k4;
            if (iy < 0 || iy >= PN) continue;
#pragma unroll
            for (int j4 = 0; j4 < 4; j4++) {
                int ix = ix0 + j4;
                if (ix < 0 || ix >= PN) continue;
                float w = wy[k4] * wx[j4];
                const float* sp = S[iy * PN + ix];
#pragma unroll
                for (int j = 0; j < 8; j++) val[j] = fmaf(w, sp[j], val[j]);
            }
        }
    }

    short hs[8], ls[8];
#pragma unroll
    for (int j = 0; j < 8; j++) {
        uint32_t u = pack_hilo(val[j]);
        hs[j] = (short)(u >> 16);
        ls[j] = (short)(u & 0xffffu);
    }
    size_t ho = ((size_t)(b * 18 + y + 1) * 18 + (x + 1)) * CC + c0;
    *(short8*)(hhi + ho) = *(short8*)hs;
    *(short8*)(hlo + ho) = *(short8*)ls;
#pragma unroll
    for (int j = 0; j < 8; j++)
        hfp[((size_t)b * CC + c0 + j) * 256 + t] = val[j];
}

// ---------------- MFMA conv3x3: LDS weights + register prefetch of next kk ----------------
template <bool FIRST>
__global__ __launch_bounds__(256)
void conv_mfma(const short* __restrict__ Whi, const short* __restrict__ Wlo,
               const short* __restrict__ hhi, const short* __restrict__ hlo,
               const float* __restrict__ hfp, const float* __restrict__ pb,
               const float* __restrict__ f, float* __restrict__ f_hat,
               float* __restrict__ lacc, int kphi) {
    __shared__ short Bsh[64 * CSTR];
    __shared__ short Bsl[64 * CSTR];
    __shared__ float red[2][16][65];
    __shared__ float lred[2];

    const int t = threadIdx.x;
    const int wave = t >> 6, lane = t & 63;
    const int quad = lane >> 4, l15 = lane & 15;
    const int pxg = wave & 1, kh = wave >> 1;
    const int cH = blockIdx.x & 1;
    const int pc = blockIdx.x >> 1;
    const int b = pc >> 3;
    const int pxbase = (pc & 7) * 32;
    const int pa = pxbase + pxg * 16 + l15;
    const int ya = pa >> 4, xa = pa & 15;

    const int row0 = t >> 4, col0 = (t & 15) * 8;  // staging coords

    floatx4 acc[4];
    floatx4 z = {0.f, 0.f, 0.f, 0.f};
#pragma unroll
    for (int nt = 0; nt < 4; nt++) acc[nt] = z;

    // register prefetch state
    short8 ph[4], pl[4];     // next-kk weight chunks
    short8 pah[2], pal[2];   // next-kk A fragments

    {   // preload kk = 0
        const size_t base = ((size_t)(kphi * 9 + 0) * CC + cH * 64) * CC;
#pragma unroll
        for (int i = 0; i < 4; i++) {
            size_t o = base + (size_t)(i * 16 + row0) * CC + col0;
            ph[i] = *(const short8*)(Whi + o);
            pl[i] = *(const short8*)(Wlo + o);
        }
        const size_t aoff = ((size_t)(b * 18 + ya + 0) * 18 + (xa + 0)) * CC;
#pragma unroll
        for (int i2 = 0; i2 < 2; i2++) {
            const int cic = kh * 2 + i2;
            pah[i2] = *(const short8*)(hhi + aoff + cic * 32 + quad * 8);
            pal[i2] = *(const short8*)(hlo + aoff + cic * 32 + quad * 8);
        }
    }

#pragma unroll 1
    for (int kk = 0; kk < 9; kk++) {
        __syncthreads();   // prior kk's ds_reads complete
#pragma unroll
        for (int i = 0; i < 4; i++) {
            *(short8*)&Bsh[(i * 16 + row0) * CSTR + col0] = ph[i];
            *(short8*)&Bsl[(i * 16 + row0) * CSTR + col0] = pl[i];
        }
        short8 ah0 = pah[0], ah1 = pah[1], al0 = pal[0], al1 = pal[1];
        __syncthreads();   // LDS ready

        if (kk < 8) {      // issue next-kk loads; results awaited at next LDS write
            const int nk = kk + 1;
            const size_t base = ((size_t)(kphi * 9 + nk) * CC + cH * 64) * CC;
#pragma unroll
            for (int i = 0; i < 4; i++) {
                size_t o = base + (size_t)(i * 16 + row0) * CC + col0;
                ph[i] = *(const short8*)(Whi + o);
                pl[i] = *(const short8*)(Wlo + o);
            }
            const int ky = nk / 3, kx = nk % 3;
            const size_t aoff = ((size_t)(b * 18 + ya + ky) * 18 + (xa + kx)) * CC;
#pragma unroll
            for (int i2 = 0; i2 < 2; i2++) {
                const int cic = kh * 2 + i2;
                pah[i2] = *(const short8*)(hhi + aoff + cic * 32 + quad * 8);
                pal[i2] = *(const short8*)(hlo + aoff + cic * 32 + quad * 8);
            }
        }

#pragma unroll
        for (int i2 = 0; i2 < 2; i2++) {
            const int cic = kh * 2 + i2;
            short8 ah = i2 ? ah1 : ah0;
            short8 al = i2 ? al1 : al0;
#pragma unroll
            for (int nt = 0; nt < 4; nt++) {
                short8 bh = *(const short8*)&Bsh[(nt * 16 + l15) * CSTR + cic * 32 + quad * 8];
                short8 bl = *(const short8*)&Bsl[(nt * 16 + l15) * CSTR + cic * 32 + quad * 8];
                acc[nt] = __builtin_amdgcn_mfma_f32_16x16x32_bf16(ah, bh, acc[nt], 0, 0, 0);
                acc[nt] = __builtin_amdgcn_mfma_f32_16x16x32_bf16(al, bh, acc[nt], 0, 0, 0);
                acc[nt] = __builtin_amdgcn_mfma_f32_16x16x32_bf16(ah, bl, acc[nt], 0, 0, 0);
            }
        }
    }

    __syncthreads();
    if (kh == 1) {
#pragma unroll
        for (int nt = 0; nt < 4; nt++)
#pragma unroll
            for (int r = 0; r < 4; r++)
                red[pxg][quad * 4 + r][nt * 16 + l15] = acc[nt][r];
    }
    __syncthreads();

    if (kh == 0) {
        const int pe = pxbase + pxg * 16 + quad * 4;
        float lsum = 0.f;
#pragma unroll
        for (int nt = 0; nt < 4; nt++) {
            int cout = cH * 64 + nt * 16 + l15;
            float bias = pb[kphi * CC + cout];
            size_t gi = ((size_t)b * CC + cout) * 256 + pe;
            float4 h4  = *(const float4*)(hfp + gi);
            float4 f4  = *(const float4*)(f + gi);
            float4 fh4 = FIRST ? make_float4(0.f, 0.f, 0.f, 0.f) : *(const float4*)(f_hat + gi);
            float c0 = acc[nt][0] + red[pxg][quad * 4 + 0][nt * 16 + l15] + bias;
            float c1 = acc[nt][1] + red[pxg][quad * 4 + 1][nt * 16 + l15] + bias;
            float c2 = acc[nt][2] + red[pxg][quad * 4 + 2][nt * 16 + l15] + bias;
            float c3 = acc[nt][3] + red[pxg][quad * 4 + 3][nt * 16 + l15] + bias;
            float o0 = fh4.x + 0.5f * h4.x + 0.5f * c0;
            float o1 = fh4.y + 0.5f * h4.y + 0.5f * c1;
            float o2 = fh4.z + 0.5f * h4.z + 0.5f * c2;
            float o3 = fh4.w + 0.5f * h4.w + 0.5f * c3;
            *(float4*)(f_hat + gi) = make_float4(o0, o1, o2, o3);
            float d0 = o0 - f4.x, d1 = o1 - f4.y, d2 = o2 - f4.z, d3 = o3 - f4.w;
            lsum += d0*d0 + d1*d1 + d2*d2 + d3*d3;
        }
#pragma unroll
        for (int off = 32; off; off >>= 1) lsum += __shfl_down(lsum, off, 64);
        if (lane == 0) lred[pxg] = lsum;
    }
    __syncthreads();
    if (t == 0) atomicAdd(lacc, lred[0] + lred[1]);
}

__global__ void finalize_kernel(const float* __restrict__ lacc, float* __restrict__ out_loss) {
    *out_loss = lacc[0] * (0.25f / (float)NELEM);   // (1+BETA)/SN * sum of means
}

extern "C" void kernel_launch(void* const* d_in, const int* in_sizes, int n_in,
                              void* d_out, int out_size, void* d_ws, size_t ws_size,
                              hipStream_t stream) {
    const float* f   = (const float*)d_in[0];
    const float* emb = (const float*)d_in[1];
    const float* pw  = (const float*)d_in[2];
    const float* pb  = (const float*)d_in[3];
    float* out = (float*)d_out;

    uint32_t* w32 = (uint32_t*)d_ws;
    short* rphi = (short*)(w32);                    // 1,048,576 shorts
    short* rplo = (short*)(w32 + 524288);
    short* ephi = (short*)(w32 + 1048576);          // 1,048,576 shorts
    short* eplo = (short*)(w32 + 1572864);
    short* Whi  = (short*)(w32 + 2097152);          // 589,824 shorts
    short* Wlo  = (short*)(w32 + 2392064);
    short* hhi  = (short*)(w32 + 2686976);          // 1,327,104 shorts
    short* hlo  = (short*)(w32 + 3350528);
    float* hfp  = (float*)(w32 + 4014080);          // 1,048,576 f
    float* esq  = (float*)(w32 + 5062656);          // 8192
    float* pbD  = (float*)(w32 + 5070848);          // 131072
    int*   pbI  = (int*)  (w32 + 5201920);          // 131072
    float* lacc = (float*)(w32 + 5332992);          // 1

    // zero halos of h planes (hhi & hlo contiguous)
    hipMemsetAsync(hhi, 0, (size_t)2 * 1327104 * sizeof(short), stream);

    esq_pack<<<512, 256, 0, stream>>>(emb, esq, ephi, eplo, lacc);
    prepack_w<<<256, 256, 0, stream>>>(pw, Whi, Wlo);

    // mirror np.linspace(1/12, 11/12, 4) exactly in float64
    double start = 1.0 / 12.0;
    double stop  = 1.0 - 1.0 / 12.0;
    double step  = (stop - start) / 3.0;
    double ticks[4] = {start, 1.0 * step + start, 2.0 * step + start, stop};

    const int pns[5]    = {1, 2, 4, 8, 16};
    const int gridy5[5] = {64, 64, 32, 16, 8};      // vslices
    const int vtPB5[5]  = {1, 1, 2, 4, 8};          // vtiles per block

    for (int si = 0; si < 5; si++) {
        int pn = pns[si];
        int N  = BB * pn * pn;
        double tt = (double)si / 4.0;
        int kphi = 0;
        double bd = fabs(ticks[0] - tt);
        for (int i = 1; i < 4; i++) {
            double d = fabs(ticks[i] - tt);
            if (d < bd) { bd = d; kphi = i; }   // np.argmin: first occurrence
        }

        if (si == 0) pool_pack<true><<<(N * CC) / 256, 256, 0, stream>>>(f, out, rphi, rplo, pn);
        else         pool_pack<false><<<(N * CC) / 256, 256, 0, stream>>>(f, out, rphi, rplo, pn);

        int qb = (N + 127) / 128;
        dim3 dgrid(qb, gridy5[si]);
        dist_mfma<<<dgrid, 256, 0, stream>>>(rphi, rplo, ephi, eplo, esq, pbD, pbI, N, vtPB5[si]);

        int vsplit = gridy5[si] * 2;
        switch (pn) {
            case 1:  upsample_pack<1><<<512, 256, 0, stream>>>(emb, pbD, pbI, vsplit, hhi, hlo, hfp); break;
            case 2:  upsample_pack<2><<<512, 256, 0, stream>>>(emb, pbD, pbI, vsplit, hhi, hlo, hfp); break;
            case 4:  upsample_pack<4><<<512, 256, 0, stream>>>(emb, pbD, pbI, vsplit, hhi, hlo, hfp); break;
            case 8:  upsample_pack<8><<<512, 256, 0, stream>>>(emb, pbD, pbI, vsplit, hhi, hlo, hfp); break;
            default: upsample_pack<16><<<512, 256, 0, stream>>>(emb, pbD, pbI, vsplit, hhi, hlo, hfp); break;
        }

        if (si == 0) conv_mfma<true><<<512, 256, 0, stream>>>(Whi, Wlo, hhi, hlo, hfp, pb, f, out, lacc, kphi);
        else         conv_mfma<false><<<512, 256, 0, stream>>>(Whi, Wlo, hhi, hlo, hfp, pb, f, out, lacc, kphi);
    }

    finalize_kernel<<<1, 1, 0, stream>>>(lacc, out + NELEM);
}

// Round 8
// 561.056 us; speedup vs baseline: 1.0218x; 1.0218x over previous
//
#include <hip/hip_runtime.h>
#include <math.h>

#define CC   128
#define HH   16
#define WW   16
#define BB   32
#define VV   8192
#define NELEM (BB*CC*HH*WW)   // 1,048,576

typedef short short8 __attribute__((ext_vector_type(8)));
typedef float floatx4 __attribute__((ext_vector_type(4)));

#define CSTR 136   // conv LDS row stride in bf16 elems (128 + 8 pad)
#define BSTR 40    // dist LDS B row stride in shorts (32 + 8 pad -> uniform 8 words/bank)

// ---------------- hi/lo bf16 split pack (RNE both) ----------------
__device__ __forceinline__ uint32_t pack_hilo(float x) {
    uint32_t u = __float_as_uint(x);
    uint32_t hb = (u + 0x7fffu + ((u >> 16) & 1u)) & 0xffff0000u;
    float hf = __uint_as_float(hb);
    float lo = x - hf;
    uint32_t ul = __float_as_uint(lo);
    uint32_t lb = ((ul + 0x7fffu + ((ul >> 16) & 1u)) >> 16) & 0xffffu;
    return hb | lb;
}

// ---------------- e_sq + codebook hi/lo plane split + lacc zero ----------------
__global__ void esq_pack(const float* __restrict__ emb, float* __restrict__ esq,
                         short* __restrict__ ephi, short* __restrict__ eplo,
                         float* __restrict__ lacc) {
    int t = blockIdx.x * 256 + threadIdx.x;
    int v = t >> 4, g = t & 15;
    const float* row = emb + (size_t)v * CC + g * 8;
    float4 a = *(const float4*)row;
    float4 b = *(const float4*)(row + 4);
    float s = a.x*a.x + a.y*a.y + a.z*a.z + a.w*a.w
            + b.x*b.x + b.y*b.y + b.z*b.z + b.w*b.w;
    s += __shfl_xor(s, 1, 64);
    s += __shfl_xor(s, 2, 64);
    s += __shfl_xor(s, 4, 64);
    s += __shfl_xor(s, 8, 64);
    if (g == 0) esq[v] = s;
    float vals[8] = {a.x, a.y, a.z, a.w, b.x, b.y, b.z, b.w};
    short hs[8], ls[8];
#pragma unroll
    for (int j = 0; j < 8; j++) {
        uint32_t u = pack_hilo(vals[j]);
        hs[j] = (short)(u >> 16);
        ls[j] = (short)(u & 0xffffu);
    }
    *(short8*)(ephi + (size_t)v * CC + g * 8) = *(short8*)hs;
    *(short8*)(eplo + (size_t)v * CC + g * 8) = *(short8*)ls;
    if (t == 0) lacc[0] = 0.f;
}

// ---------------- pre-transpose + split conv weights: Wt[kphi][kk][cout][cin] ----------------
__global__ void prepack_w(const float* __restrict__ pw, short* __restrict__ Whi,
                          short* __restrict__ Wlo) {
    int id = blockIdx.x * 256 + threadIdx.x;      // 65536 = 4*128*128
    int ci = id & 127, cout = (id >> 7) & 127, kp = id >> 14;
    const float* src = pw + ((size_t)(kp * CC + cout) * CC + ci) * 9;
#pragma unroll
    for (int kk = 0; kk < 9; kk++) {
        uint32_t u = pack_hilo(src[kk]);
        size_t o = ((size_t)(kp * 9 + kk) * CC + cout) * CC + ci;
        Whi[o] = (short)(u >> 16);
        Wlo[o] = (short)(u & 0xffffu);
    }
}

// ---------------- pooled residual (f - f_hat) -> hi/lo planes ----------------
template <bool FIRSTP>
__global__ void pool_pack(const float* __restrict__ f, const float* __restrict__ fh,
                          short* __restrict__ rh, short* __restrict__ rl, int pn) {
    int id = blockIdx.x * 256 + threadIdx.x;
    int c = id % CC;
    int n = id / CC;
    int px = n % pn;
    int py = (n / pn) % pn;
    int b  = n / (pn * pn);
    int s  = HH / pn;
    size_t o = (((size_t)b * CC + c) * HH + py * s) * WW + px * s;
    float acc = 0.f;
    for (int dy = 0; dy < s; dy++)
        for (int dx = 0; dx < s; dx++)
            acc += FIRSTP ? f[o + dy * WW + dx] : (f[o + dy * WW + dx] - fh[o + dy * WW + dx]);
    uint32_t u = pack_hilo(acc * (1.f / (float)(s * s)));
    rh[id] = (short)(u >> 16);
    rl[id] = (short)(u & 0xffffu);
}

// ---------------- MFMA distance v5: LDS double-buffered B, per-kc A, 3 products ----------------
// grid (qb, vslices); block 256 = 4 waves: qh=w&1, vh=w>>1. Wave: 64 q x 64 v quadrant.
__global__ __launch_bounds__(256, 3)
void dist_mfma(const short* __restrict__ rphi, const short* __restrict__ rplo,
               const short* __restrict__ ephi, const short* __restrict__ eplo,
               const float* __restrict__ esq,
               float* __restrict__ pbD, int* __restrict__ pbI,
               int N, int vtPB) {
    __shared__ short Bh[2][128 * BSTR];   // 2 x 10240 B
    __shared__ short Bl[2][128 * BSTR];

    const int tid  = threadIdx.x;
    const int wave = tid >> 6, lane = tid & 63;
    const int quad = lane >> 4, l15 = lane & 15;
    const int qh = wave & 1, vh = wave >> 1;
    const int qb0 = blockIdx.x * 128;
    const int vslices = gridDim.y;
    const int vbase = blockIdx.y * vtPB * 128;

    // staging role: each thread moves 2 rows' 8-short chunk (hi + lo)
    const int srow0 = tid >> 2;          // 0..63
    const int spart = (tid & 3) * 8;     // 0,8,16,24

    size_t arow[4];
#pragma unroll
    for (int ti = 0; ti < 4; ti++)
        arow[ti] = (size_t)(qb0 + qh * 64 + ti * 16 + l15) * CC + quad * 8;

    float bD[4][4];
    int   bI[4][4];
#pragma unroll
    for (int ti = 0; ti < 4; ti++)
#pragma unroll
        for (int r = 0; r < 4; r++) { bD[ti][r] = INFINITY; bI[ti][r] = 0; }

#pragma unroll 1
    for (int vt = 0; vt < vtPB; vt++) {
        const int v0 = vbase + vt * 128;
        floatx4 acc[4][4];
        floatx4 z = {0.f, 0.f, 0.f, 0.f};
#pragma unroll
        for (int ti = 0; ti < 4; ti++)
#pragma unroll
            for (int tj = 0; tj < 4; tj++) acc[ti][tj] = z;

        {   // stage kc=0 into buf 0 (safe: prior vt's buf0 readers passed kc=3 barrier)
#pragma unroll
            for (int i = 0; i < 2; i++) {
                int row = srow0 + i * 64;
                size_t g = (size_t)(v0 + row) * CC + spart;   // kc=0
                *(short8*)&Bh[0][row * BSTR + spart] = *(const short8*)(ephi + g);
                *(short8*)&Bl[0][row * BSTR + spart] = *(const short8*)(eplo + g);
            }
        }

#pragma unroll 1
        for (int kc = 0; kc < 4; kc++) {
            __syncthreads();   // buf[kc&1] visible; buf[(kc+1)&1] readers (kc-1) drained
            if (kc < 3) {
                const int nb = (kc + 1) & 1;
#pragma unroll
                for (int i = 0; i < 2; i++) {
                    int row = srow0 + i * 64;
                    size_t g = (size_t)(v0 + row) * CC + (kc + 1) * 32 + spart;
                    *(short8*)&Bh[nb][row * BSTR + spart] = *(const short8*)(ephi + g);
                    *(short8*)&Bl[nb][row * BSTR + spart] = *(const short8*)(eplo + g);
                }
            }

            const int ko = kc * 32;
            short8 av[4], aw[4];
#pragma unroll
            for (int ti = 0; ti < 4; ti++) {
                av[ti] = *(const short8*)(rphi + arow[ti] + ko);
                aw[ti] = *(const short8*)(rplo + arow[ti] + ko);
            }
            const short* bufh = Bh[kc & 1];
            const short* bufl = Bl[kc & 1];
#pragma unroll
            for (int tj = 0; tj < 4; tj++) {
                const int brl = (vh * 64 + tj * 16 + l15) * BSTR + quad * 8;
                short8 bh = *(const short8*)&bufh[brl];
                short8 bl = *(const short8*)&bufl[brl];
#pragma unroll
                for (int ti = 0; ti < 4; ti++) {
                    acc[ti][tj] = __builtin_amdgcn_mfma_f32_16x16x32_bf16(av[ti], bh, acc[ti][tj], 0, 0, 0);
                    acc[ti][tj] = __builtin_amdgcn_mfma_f32_16x16x32_bf16(aw[ti], bh, acc[ti][tj], 0, 0, 0);
                    acc[ti][tj] = __builtin_amdgcn_mfma_f32_16x16x32_bf16(av[ti], bl, acc[ti][tj], 0, 0, 0);
                }
            }
        }

        // dist = esq - 2*dot; v ascending per lane -> strict < keeps first min
#pragma unroll
        for (int tj = 0; tj < 4; tj++) {
            int vg = v0 + vh * 64 + tj * 16 + l15;
            float ev = esq[vg];
#pragma unroll
            for (int ti = 0; ti < 4; ti++)
#pragma unroll
                for (int r = 0; r < 4; r++) {
                    float d = fmaf(-2.f, acc[ti][tj][r], ev);
                    if (d < bD[ti][r]) { bD[ti][r] = d; bI[ti][r] = vg; }
                }
        }
    }

    // cross-lane reduce within 16-lane groups (same q, different v), tie -> lower v
#pragma unroll
    for (int ti = 0; ti < 4; ti++)
#pragma unroll
        for (int r = 0; r < 4; r++) {
            float d = bD[ti][r];
            int   v = bI[ti][r];
#pragma unroll
            for (int m = 1; m <= 8; m <<= 1) {
                float od = __shfl_xor(d, m, 64);
                int   ov = __shfl_xor(v, m, 64);
                if (od < d || (od == d && ov < v)) { d = od; v = ov; }
            }
            if (l15 == 0) {
                int q = qb0 + qh * 64 + ti * 16 + quad * 4 + r;
                if (q < N) {
                    size_t o = (size_t)q * (vslices * 2) + blockIdx.y * 2 + vh;
                    pbD[o] = d;
                    pbI[o] = v;
                }
            }
        }
}

// ---------------- Keys cubic a=-0.5 (matches jax) ----------------
__device__ __forceinline__ float cubic_k(float x) {
    if (x <= 1.f) return (1.5f * x - 2.5f) * x * x + 1.f;
    if (x < 2.f)  return ((-0.5f * x + 2.5f) * x - 4.f) * x + 2.f;
    return 0.f;
}

// ---------------- fused argmin + upsample -> h planes ----------------
template <int PN>
__global__ __launch_bounds__(256)
void upsample_pack(const float* __restrict__ emb,
                   const float* __restrict__ pbD, const int* __restrict__ pbI, int vsplit,
                   short* __restrict__ hhi, short* __restrict__ hlo,
                   float* __restrict__ hfp) {
    const int t = threadIdx.x;
    const int x = t & 15, y = t >> 4;
    const int b = blockIdx.x >> 4;
    const int c0 = (blockIdx.x & 15) * 8;

    float val[8];

    if (PN == 16) {
        int q = b * 256 + t;
        float bd = pbD[(size_t)q * vsplit];
        int   bi = pbI[(size_t)q * vsplit];
        for (int j = 1; j < vsplit; j++) {
            float d  = pbD[(size_t)q * vsplit + j];
            int   i2 = pbI[(size_t)q * vsplit + j];
            if (d < bd || (d == bd && i2 < bi)) { bd = d; bi = i2; }
        }
        float4 v0 = *(const float4*)(emb + (size_t)bi * CC + c0);
        float4 v1 = *(const float4*)(emb + (size_t)bi * CC + c0 + 4);
        val[0]=v0.x; val[1]=v0.y; val[2]=v0.z; val[3]=v0.w;
        val[4]=v1.x; val[5]=v1.y; val[6]=v1.z; val[7]=v1.w;
    } else {
        __shared__ int idxL[PN * PN];
        __shared__ float S[PN * PN][8];
        if (t < PN * PN) {
            int q = b * PN * PN + t;
            float bd = pbD[(size_t)q * vsplit];
            int   bi = pbI[(size_t)q * vsplit];
            for (int j = 1; j < vsplit; j++) {
                float d  = pbD[(size_t)q * vsplit + j];
                int   i2 = pbI[(size_t)q * vsplit + j];
                if (d < bd || (d == bd && i2 < bi)) { bd = d; bi = i2; }
            }
            idxL[t] = bi;
        }
        __syncthreads();
        if (t < PN * PN) {
            float4 v0 = *(const float4*)(emb + (size_t)idxL[t] * CC + c0);
            float4 v1 = *(const float4*)(emb + (size_t)idxL[t] * CC + c0 + 4);
            S[t][0]=v0.x; S[t][1]=v0.y; S[t][2]=v0.z; S[t][3]=v0.w;
            S[t][4]=v1.x; S[t][5]=v1.y; S[t][6]=v1.z; S[t][7]=v1.w;
        }
        __syncthreads();

        const float sc = (float)PN / 16.f;
        float sy = (y + 0.5f) * sc - 0.5f;
        float sx = (x + 0.5f) * sc - 0.5f;
        int iy0 = (int)floorf(sy) - 1;
        int ix0 = (int)floorf(sx) - 1;
        float wy[4], wx[4];
        float ssy = 0.f, ssx = 0.f;
#pragma unroll
        for (int k = 0; k < 4; k++) {
            int iy = iy0 + k, ix = ix0 + k;
            float a = (iy >= 0 && iy < PN) ? cubic_k(fabsf(sy - (float)iy)) : 0.f;
            float bb = (ix >= 0 && ix < PN) ? cubic_k(fabsf(sx - (float)ix)) : 0.f;
            wy[k] = a; ssy += a;
            wx[k] = bb; ssx += bb;
        }
        float ry = 1.f / ssy, rx = 1.f / ssx;
#pragma unroll
        for (int k = 0; k < 4; k++) { wy[k] *= ry; wx[k] *= rx; }

#pragma unroll
        for (int j = 0; j < 8; j++) val[j] = 0.f;
#pragma unroll
        for (int k4 = 0; k4 < 4; k4++) {
            int iy = iy0 + k4;
            if (iy < 0 || iy >= PN) continue;
#pragma unroll
            for (int j4 = 0; j4 < 4; j4++) {
                int ix = ix0 + j4;
                if (ix < 0 || ix >= PN) continue;
                float w = wy[k4] * wx[j4];
                const float* sp = S[iy * PN + ix];
#pragma unroll
                for (int j = 0; j < 8; j++) val[j] = fmaf(w, sp[j], val[j]);
            }
        }
    }

    short hs[8], ls[8];
#pragma unroll
    for (int j = 0; j < 8; j++) {
        uint32_t u = pack_hilo(val[j]);
        hs[j] = (short)(u >> 16);
        ls[j] = (short)(u & 0xffffu);
    }
    size_t ho = ((size_t)(b * 18 + y + 1) * 18 + (x + 1)) * CC + c0;
    *(short8*)(hhi + ho) = *(short8*)hs;
    *(short8*)(hlo + ho) = *(short8*)ls;
#pragma unroll
    for (int j = 0; j < 8; j++)
        hfp[((size_t)b * CC + c0 + j) * 256 + t] = val[j];
}

// ---------------- MFMA conv3x3: LDS weights + register prefetch of next kk ----------------
template <bool FIRST>
__global__ __launch_bounds__(256)
void conv_mfma(const short* __restrict__ Whi, const short* __restrict__ Wlo,
               const short* __restrict__ hhi, const short* __restrict__ hlo,
               const float* __restrict__ hfp, const float* __restrict__ pb,
               const float* __restrict__ f, float* __restrict__ f_hat,
               float* __restrict__ lacc, int kphi) {
    __shared__ short Bsh[64 * CSTR];
    __shared__ short Bsl[64 * CSTR];
    __shared__ float red[2][16][65];
    __shared__ float lred[2];

    const int t = threadIdx.x;
    const int wave = t >> 6, lane = t & 63;
    const int quad = lane >> 4, l15 = lane & 15;
    const int pxg = wave & 1, kh = wave >> 1;
    const int cH = blockIdx.x & 1;
    const int pc = blockIdx.x >> 1;
    const int b = pc >> 3;
    const int pxbase = (pc & 7) * 32;
    const int pa = pxbase + pxg * 16 + l15;
    const int ya = pa >> 4, xa = pa & 15;

    const int row0 = t >> 4, col0 = (t & 15) * 8;  // staging coords

    floatx4 acc[4];
    floatx4 z = {0.f, 0.f, 0.f, 0.f};
#pragma unroll
    for (int nt = 0; nt < 4; nt++) acc[nt] = z;

    short8 ph[4], pl[4];     // next-kk weight chunks
    short8 pah[2], pal[2];   // next-kk A fragments

    {   // preload kk = 0
        const size_t base = ((size_t)(kphi * 9 + 0) * CC + cH * 64) * CC;
#pragma unroll
        for (int i = 0; i < 4; i++) {
            size_t o = base + (size_t)(i * 16 + row0) * CC + col0;
            ph[i] = *(const short8*)(Whi + o);
            pl[i] = *(const short8*)(Wlo + o);
        }
        const size_t aoff = ((size_t)(b * 18 + ya + 0) * 18 + (xa + 0)) * CC;
#pragma unroll
        for (int i2 = 0; i2 < 2; i2++) {
            const int cic = kh * 2 + i2;
            pah[i2] = *(const short8*)(hhi + aoff + cic * 32 + quad * 8);
            pal[i2] = *(const short8*)(hlo + aoff + cic * 32 + quad * 8);
        }
    }

#pragma unroll 1
    for (int kk = 0; kk < 9; kk++) {
        __syncthreads();
#pragma unroll
        for (int i = 0; i < 4; i++) {
            *(short8*)&Bsh[(i * 16 + row0) * CSTR + col0] = ph[i];
            *(short8*)&Bsl[(i * 16 + row0) * CSTR + col0] = pl[i];
        }
        short8 ah0 = pah[0], ah1 = pah[1], al0 = pal[0], al1 = pal[1];
        __syncthreads();

        if (kk < 8) {
            const int nk = kk + 1;
            const size_t base = ((size_t)(kphi * 9 + nk) * CC + cH * 64) * CC;
#pragma unroll
            for (int i = 0; i < 4; i++) {
                size_t o = base + (size_t)(i * 16 + row0) * CC + col0;
                ph[i] = *(const short8*)(Whi + o);
                pl[i] = *(const short8*)(Wlo + o);
            }
            const int ky = nk / 3, kx = nk % 3;
            const size_t aoff = ((size_t)(b * 18 + ya + ky) * 18 + (xa + kx)) * CC;
#pragma unroll
            for (int i2 = 0; i2 < 2; i2++) {
                const int cic = kh * 2 + i2;
                pah[i2] = *(const short8*)(hhi + aoff + cic * 32 + quad * 8);
                pal[i2] = *(const short8*)(hlo + aoff + cic * 32 + quad * 8);
            }
        }

#pragma unroll
        for (int i2 = 0; i2 < 2; i2++) {
            const int cic = kh * 2 + i2;
            short8 ah = i2 ? ah1 : ah0;
            short8 al = i2 ? al1 : al0;
#pragma unroll
            for (int nt = 0; nt < 4; nt++) {
                short8 bh = *(const short8*)&Bsh[(nt * 16 + l15) * CSTR + cic * 32 + quad * 8];
                short8 bl = *(const short8*)&Bsl[(nt * 16 + l15) * CSTR + cic * 32 + quad * 8];
                acc[nt] = __builtin_amdgcn_mfma_f32_16x16x32_bf16(ah, bh, acc[nt], 0, 0, 0);
                acc[nt] = __builtin_amdgcn_mfma_f32_16x16x32_bf16(al, bh, acc[nt], 0, 0, 0);
                acc[nt] = __builtin_amdgcn_mfma_f32_16x16x32_bf16(ah, bl, acc[nt], 0, 0, 0);
            }
        }
    }

    __syncthreads();
    if (kh == 1) {
#pragma unroll
        for (int nt = 0; nt < 4; nt++)
#pragma unroll
            for (int r = 0; r < 4; r++)
                red[pxg][quad * 4 + r][nt * 16 + l15] = acc[nt][r];
    }
    __syncthreads();

    if (kh == 0) {
        const int pe = pxbase + pxg * 16 + quad * 4;
        float lsum = 0.f;
#pragma unroll
        for (int nt = 0; nt < 4; nt++) {
            int cout = cH * 64 + nt * 16 + l15;
            float bias = pb[kphi * CC + cout];
            size_t gi = ((size_t)b * CC + cout) * 256 + pe;
            float4 h4  = *(const float4*)(hfp + gi);
            float4 f4  = *(const float4*)(f + gi);
            float4 fh4 = FIRST ? make_float4(0.f, 0.f, 0.f, 0.f) : *(const float4*)(f_hat + gi);
            float c0 = acc[nt][0] + red[pxg][quad * 4 + 0][nt * 16 + l15] + bias;
            float c1 = acc[nt][1] + red[pxg][quad * 4 + 1][nt * 16 + l15] + bias;
            float c2 = acc[nt][2] + red[pxg][quad * 4 + 2][nt * 16 + l15] + bias;
            float c3 = acc[nt][3] + red[pxg][quad * 4 + 3][nt * 16 + l15] + bias;
            float o0 = fh4.x + 0.5f * h4.x + 0.5f * c0;
            float o1 = fh4.y + 0.5f * h4.y + 0.5f * c1;
            float o2 = fh4.z + 0.5f * h4.z + 0.5f * c2;
            float o3 = fh4.w + 0.5f * h4.w + 0.5f * c3;
            *(float4*)(f_hat + gi) = make_float4(o0, o1, o2, o3);
            float d0 = o0 - f4.x, d1 = o1 - f4.y, d2 = o2 - f4.z, d3 = o3 - f4.w;
            lsum += d0*d0 + d1*d1 + d2*d2 + d3*d3;
        }
#pragma unroll
        for (int off = 32; off; off >>= 1) lsum += __shfl_down(lsum, off, 64);
        if (lane == 0) lred[pxg] = lsum;
    }
    __syncthreads();
    if (t == 0) atomicAdd(lacc, lred[0] + lred[1]);
}

__global__ void finalize_kernel(const float* __restrict__ lacc, float* __restrict__ out_loss) {
    *out_loss = lacc[0] * (0.25f / (float)NELEM);   // (1+BETA)/SN * sum of means
}

extern "C" void kernel_launch(void* const* d_in, const int* in_sizes, int n_in,
                              void* d_out, int out_size, void* d_ws, size_t ws_size,
                              hipStream_t stream) {
    const float* f   = (const float*)d_in[0];
    const float* emb = (const float*)d_in[1];
    const float* pw  = (const float*)d_in[2];
    const float* pb  = (const float*)d_in[3];
    float* out = (float*)d_out;

    uint32_t* w32 = (uint32_t*)d_ws;
    short* rphi = (short*)(w32);                    // 1,048,576 shorts
    short* rplo = (short*)(w32 + 524288);
    short* ephi = (short*)(w32 + 1048576);          // 1,048,576 shorts
    short* eplo = (short*)(w32 + 1572864);
    short* Whi  = (short*)(w32 + 2097152);          // 589,824 shorts
    short* Wlo  = (short*)(w32 + 2392064);
    short* hhi  = (short*)(w32 + 2686976);          // 1,327,104 shorts
    short* hlo  = (short*)(w32 + 3350528);
    float* hfp  = (float*)(w32 + 4014080);          // 1,048,576 f
    float* esq  = (float*)(w32 + 5062656);          // 8192
    float* pbD  = (float*)(w32 + 5070848);          // 262144
    int*   pbI  = (int*)  (w32 + 5332992);          // 262144
    float* lacc = (float*)(w32 + 5595136);          // 1

    // zero halos of h planes (hhi & hlo contiguous)
    hipMemsetAsync(hhi, 0, (size_t)2 * 1327104 * sizeof(short), stream);

    esq_pack<<<512, 256, 0, stream>>>(emb, esq, ephi, eplo, lacc);
    prepack_w<<<256, 256, 0, stream>>>(pw, Whi, Wlo);

    // mirror np.linspace(1/12, 11/12, 4) exactly in float64
    double start = 1.0 / 12.0;
    double stop  = 1.0 - 1.0 / 12.0;
    double step  = (stop - start) / 3.0;
    double ticks[4] = {start, 1.0 * step + start, 2.0 * step + start, stop};

    const int pns[5]    = {1, 2, 4, 8, 16};
    const int gridy5[5] = {64, 64, 64, 32, 16};     // vslices
    const int vtPB5[5]  = {1, 1, 1, 2, 4};          // vtiles per block

    for (int si = 0; si < 5; si++) {
        int pn = pns[si];
        int N  = BB * pn * pn;
        double tt = (double)si / 4.0;
        int kphi = 0;
        double bd = fabs(ticks[0] - tt);
        for (int i = 1; i < 4; i++) {
            double d = fabs(ticks[i] - tt);
            if (d < bd) { bd = d; kphi = i; }   // np.argmin: first occurrence
        }

        if (si == 0) pool_pack<true><<<(N * CC) / 256, 256, 0, stream>>>(f, out, rphi, rplo, pn);
        else         pool_pack<false><<<(N * CC) / 256, 256, 0, stream>>>(f, out, rphi, rplo, pn);

        int qb = (N + 127) / 128;
        dim3 dgrid(qb, gridy5[si]);
        dist_mfma<<<dgrid, 256, 0, stream>>>(rphi, rplo, ephi, eplo, esq, pbD, pbI, N, vtPB5[si]);

        int vsplit = gridy5[si] * 2;
        switch (pn) {
            case 1:  upsample_pack<1><<<512, 256, 0, stream>>>(emb, pbD, pbI, vsplit, hhi, hlo, hfp); break;
            case 2:  upsample_pack<2><<<512, 256, 0, stream>>>(emb, pbD, pbI, vsplit, hhi, hlo, hfp); break;
            case 4:  upsample_pack<4><<<512, 256, 0, stream>>>(emb, pbD, pbI, vsplit, hhi, hlo, hfp); break;
            case 8:  upsample_pack<8><<<512, 256, 0, stream>>>(emb, pbD, pbI, vsplit, hhi, hlo, hfp); break;
            default: upsample_pack<16><<<512, 256, 0, stream>>>(emb, pbD, pbI, vsplit, hhi, hlo, hfp); break;
        }

        if (si == 0) conv_mfma<true><<<512, 256, 0, stream>>>(Whi, Wlo, hhi, hlo, hfp, pb, f, out, lacc, kphi);
        else         conv_mfma<false><<<512, 256, 0, stream>>>(Whi, Wlo, hhi, hlo, hfp, pb, f, out, lacc, kphi);
    }

    finalize_kernel<<<1, 1, 0, stream>>>(lacc, out + NELEM);
}